// Round 11
// baseline (188.523 us; speedup 1.0000x reference)
//
#include <hip/hip_runtime.h>
#include <hip/hip_bf16.h>

typedef __bf16 bf16;
typedef bf16 bf16x8 __attribute__((ext_vector_type(8)));
typedef bf16 bf16x4 __attribute__((ext_vector_type(4)));
typedef float f32x4 __attribute__((ext_vector_type(4)));

#define BAR()   asm volatile("s_barrier" ::: "memory")
#define LGKM0() asm volatile("s_waitcnt lgkmcnt(0)" ::: "memory")
#define VMW3()  asm volatile("s_waitcnt vmcnt(3)" ::: "memory")
#define VMW0()  asm volatile("s_waitcnt vmcnt(0)" ::: "memory")

__device__ __forceinline__ void gload_lds16(const void* g, void* l) {
    __builtin_amdgcn_global_load_lds(
        (const __attribute__((address_space(1))) void*)g,
        (__attribute__((address_space(3))) void*)l, 16, 0, 0);
}

// ---------------------------------------------------------------------------
// 128x256 NT-GEMM core, BK=32, 8 waves (2M x 4N), 48KB double-buffered LDS.
// Verified r6/r8 schedule: stage tile t+1 (3 gloads), vmcnt(3), BAR,
// 8x ds_read_b128 (conflict-free via chunk XOR), 16 MFMA, lgkm0, BAR.
// Swizzle: LDS chunk c holds global chunk c ^ ((row>>1)&3); applied on the
// global source (linear gload_lds dest) and on ds_reads (both-sides rule).
// Buffers: A[128][32] @0, B[256][32] @8KB; bufs at 0/24KB.
// ---------------------------------------------------------------------------
__device__ __forceinline__
void gemm_core_bk32(const bf16* __restrict__ Ag, const bf16* __restrict__ Bg,
                    const int ldA, const int ldB, const int NT,
                    char* smem, f32x4 (&acc)[4][4])
{
    const int t    = threadIdx.x;          // 0..511
    const int lane = t & 63;
    const int wid  = t >> 6;
    const int wrow = wid >> 2;
    const int wcol = wid & 3;
    const int rl   = lane & 15;
    const int hi   = lane >> 4;
    const int ko   = ((hi ^ ((rl >> 1) & 3)) << 4);

    const int arow = t >> 2;
    const int sch  = (t & 3) ^ ((t >> 3) & 3);
    const bf16* pA  = Ag + (long long)arow * ldA + sch * 8;
    const bf16* pB0 = Bg + (long long)arow * ldB + sch * 8;
    const bf16* pB1 = pB0 + 128ll * ldB;
    char* uw = smem + (t & ~63) * 16;

#define STG32(tt) { char* db = uw + ((tt) & 1) * 24576; const int kk = (tt) * 32; \
    gload_lds16(pA  + kk, db); \
    gload_lds16(pB0 + kk, db + 8192); \
    gload_lds16(pB1 + kk, db + 16384); }

    STG32(0);
    for (int tt = 0; tt < NT; ++tt) {
        if (tt + 1 < NT) {
            STG32(tt + 1);
            VMW3();
        } else {
            VMW0();
        }
        BAR();
        const char* aB = smem + (tt & 1) * 24576;
        const char* bB = aB + 8192;
        bf16x8 af[4], bfr[4];
#pragma unroll
        for (int m = 0; m < 4; ++m)
            af[m]  = *(const bf16x8*)(aB + (wrow * 64 + m * 16 + rl) * 64 + ko);
#pragma unroll
        for (int n = 0; n < 4; ++n)
            bfr[n] = *(const bf16x8*)(bB + (wcol * 64 + n * 16 + rl) * 64 + ko);
        __builtin_amdgcn_s_setprio(1);
#pragma unroll
        for (int m = 0; m < 4; ++m)
#pragma unroll
            for (int n = 0; n < 4; ++n)
                acc[m][n] = __builtin_amdgcn_mfma_f32_16x16x32_bf16(
                                af[m], bfr[n], acc[m][n], 0, 0, 0);
        __builtin_amdgcn_s_setprio(0);
        LGKM0();
        BAR();
    }
#undef STG32
}

// ---------------------------------------------------------------------------
// Merged QKV projections, 128x256 tiles: grid (12, 64), XCD-remapped.
// A = pre-converted bf16 X.  mat==2 (V): LDS-staged transpose epilogue.
// ---------------------------------------------------------------------------
__global__ __launch_bounds__(512, 4)
void gemm_qkv(const bf16* __restrict__ Xq, const bf16* __restrict__ Xk,
              const bf16* __restrict__ Xv,
              const bf16* __restrict__ Wt3,
              float* __restrict__ outQ, bf16* __restrict__ Qb,
              bf16* __restrict__ Kb, bf16* __restrict__ Vt)
{
    extern __shared__ char smem[];
    const int id0 = blockIdx.x + 12 * blockIdx.y;
    const int T   = (id0 & 7) * 96 + (id0 >> 3);
    const int bxn = T % 12, byn = T / 12;
    const int mat = bxn >> 2, nc = bxn & 3;

    const bf16* A = (mat == 0 ? Xq : mat == 1 ? Xk : Xv) + (long long)byn * 128 * 1024;
    const bf16* B = Wt3 + (long long)mat * 1024 * 1024 + (long long)nc * 256 * 1024;
    f32x4 acc[4][4] = {};
    gemm_core_bk32(A, B, 1024, 1024, 32, smem, acc);

    const int t = threadIdx.x, lane = t & 63, wid = t >> 6;
    const int wr = (wid >> 2) * 64, wc = (wid & 3) * 64;
    const int rl = lane & 15, rg4 = (lane >> 4) * 4;

    if (mat != 2) {
#pragma unroll
        for (int m = 0; m < 4; ++m)
#pragma unroll
            for (int n = 0; n < 4; ++n)
#pragma unroll
                for (int j = 0; j < 4; ++j) {
                    const int row = byn * 128 + wr + m * 16 + rg4 + j;
                    const int col = nc * 256 + wc + n * 16 + rl;
                    const float v = acc[m][n][j];
                    if (mat == 0) { outQ[(long long)row * 1024 + col] = v;
                                    Qb[(long long)row * 1024 + col] = (bf16)v; }
                    else Kb[(long long)row * 1024 + col] = (bf16)v;
                }
    } else {
        // V: transpose via LDS (two 128-col halves; swizzled [128][128] bf16)
        char* lT = smem;
#pragma unroll
        for (int h = 0; h < 2; ++h) {
            BAR();
            if ((wc >> 7) == h) {
#pragma unroll
                for (int m = 0; m < 4; ++m)
#pragma unroll
                    for (int n = 0; n < 4; ++n) {
                        const int cp = (wc & 127) + n * 16 + rl;      // 0..127
                        const int rb = wr + m * 16 + rg4;             // 0..124
                        bf16x4 v;
                        v[0] = (bf16)acc[m][n][0]; v[1] = (bf16)acc[m][n][1];
                        v[2] = (bf16)acc[m][n][2]; v[3] = (bf16)acc[m][n][3];
                        *(bf16x4*)(lT + cp * 256 + ((rb * 2) ^ ((cp & 7) << 4))) = v;
                    }
            }
            BAR();
            const int c2 = t >> 2;
#pragma unroll
            for (int it = 0; it < 4; ++it) {
                const int q = (t & 3) + it * 4;                       // 0..15
                bf16x8 v = *(const bf16x8*)(lT + c2 * 256 + ((q << 4) ^ ((c2 & 7) << 4)));
                *(bf16x8*)(Vt + (long long)(nc * 256 + h * 128 + c2) * 8192
                              + byn * 128 + q * 8) = v;
            }
        }
    }
}

// ---------------------------------------------------------------------------
// QK^T causal, 128x256 tiles: grid (8, 16, 4); skip fully-masked tiles.
// Writes bf16 scores (ld 2048).
// ---------------------------------------------------------------------------
__global__ __launch_bounds__(512, 4)
void gemm_sc(const bf16* __restrict__ Qb, const bf16* __restrict__ Kb,
             bf16* __restrict__ scores, float scale)
{
    if (2 * blockIdx.x > blockIdx.y) return;
    extern __shared__ char smem[];
    const int bx = blockIdx.x, by = blockIdx.y, bz = blockIdx.z;
    const long long boff = (long long)bz * 2048 * 1024;
    f32x4 acc[4][4] = {};
    gemm_core_bk32(Qb + boff + (long long)by * 128 * 1024,
                   Kb + boff + (long long)bx * 256 * 1024, 1024, 1024, 32, smem, acc);

    const int t = threadIdx.x, lane = t & 63, wid = t >> 6;
    const int wr = (wid >> 2) * 64, wc = (wid & 3) * 64;
    const int rl = lane & 15, rg4 = (lane >> 4) * 4;
    bf16* Cb = scores + (long long)bz * 2048 * 2048;
#pragma unroll
    for (int m = 0; m < 4; ++m)
#pragma unroll
        for (int n = 0; n < 4; ++n)
#pragma unroll
            for (int j = 0; j < 4; ++j) {
                const int row = by * 128 + wr + m * 16 + rg4 + j;
                const int col = bx * 256 + wc + n * 16 + rl;
                Cb[(long long)row * 2048 + col] = (bf16)(acc[m][n][j] * scale);
            }
}

// ---------------------------------------------------------------------------
// PV: 128x256 tiles, grid 256 -> (bz, bx 0..3, by 0..15 interleaved).
// A = P (bf16, ld 2048), B = Vt (ld 8192), NT = (by+1)*4 (K-limit).
// ---------------------------------------------------------------------------
__global__ __launch_bounds__(512, 4)
void gemm_pv(const bf16* __restrict__ P, const bf16* __restrict__ Vt,
             float* __restrict__ outA)
{
    extern __shared__ char smem[];
    const int F = blockIdx.x;
    const int bz = F & 3;
    const int bx = (F >> 2) & 3;
    const int byr = F >> 4;                       // 0..15
    const int by = (byr & 1) ? (byr >> 1) : (15 - (byr >> 1));
    f32x4 acc[4][4] = {};
    gemm_core_bk32(P + (long long)bz * 2048 * 2048 + (long long)by * 128 * 2048,
                   Vt + (long long)bx * 256 * 8192 + (long long)bz * 2048,
                   2048, 8192, (by + 1) * 4, smem, acc);

    const int t = threadIdx.x, lane = t & 63, wid = t >> 6;
    const int wr = (wid >> 2) * 64, wc = (wid & 3) * 64;
    const int rl = lane & 15, rg4 = (lane >> 4) * 4;
    float* Cb = outA + (long long)bz * 2048 * 1024;
#pragma unroll
    for (int m = 0; m < 4; ++m)
#pragma unroll
        for (int n = 0; n < 4; ++n)
#pragma unroll
            for (int j = 0; j < 4; ++j) {
                const int row = by * 128 + wr + m * 16 + rg4 + j;
                const int col = bx * 256 + wc + n * 16 + rl;
                Cb[(long long)row * 1024 + col] = acc[m][n][j];
            }
}

// ---------------------------------------------------------------------------
// f32 -> bf16 convert for the three X inputs (32B -> 16B per thread).
// ---------------------------------------------------------------------------
__global__ __launch_bounds__(256)
void convert_x(const float* __restrict__ X0, const float* __restrict__ X1,
               const float* __restrict__ X2,
               bf16* __restrict__ Y0, bf16* __restrict__ Y1, bf16* __restrict__ Y2)
{
    const int which = blockIdx.x >> 12;
    const long long base = (((long long)(blockIdx.x & 4095)) * 256 + threadIdx.x) * 8;
    const float* X = which == 0 ? X0 : which == 1 ? X1 : X2;
    bf16*       Y = which == 0 ? Y0 : which == 1 ? Y1 : Y2;
    float4 a = *(const float4*)(X + base);
    float4 b = *(const float4*)(X + base + 4);
    bf16x8 v;
    v[0] = (bf16)a.x; v[1] = (bf16)a.y; v[2] = (bf16)a.z; v[3] = (bf16)a.w;
    v[4] = (bf16)b.x; v[5] = (bf16)b.y; v[6] = (bf16)b.z; v[7] = (bf16)b.w;
    *(bf16x8*)(Y + base) = v;
}

// ---------------------------------------------------------------------------
// Transpose-convert all three W into contiguous Wt3[mat][n][k]: grid (32,32,3).
// ---------------------------------------------------------------------------
__global__ __launch_bounds__(256)
void transpose_w3(const float* __restrict__ W0, const float* __restrict__ W1,
                  const float* __restrict__ W2, bf16* __restrict__ Wt3)
{
    __shared__ float tile[32][33];
    const int w = blockIdx.z;
    const float* W = w == 0 ? W0 : w == 1 ? W1 : W2;
    bf16* Wt = Wt3 + (size_t)w * 1024 * 1024;
    const int bx = blockIdx.x * 32;
    const int by = blockIdx.y * 32;
    const int tx = threadIdx.x;
    const int ty = threadIdx.y;
    for (int i = ty; i < 32; i += 8)
        tile[i][tx] = W[(size_t)(by + i) * 1024 + bx + tx];
    __syncthreads();
    for (int i = ty; i < 32; i += 8)
        Wt[(size_t)(bx + i) * 1024 + by + tx] = (bf16)tile[tx][i];
}

// ---------------------------------------------------------------------------
// Causal row softmax over bf16 scores, in place, pure register pass.
// ---------------------------------------------------------------------------
__global__ __launch_bounds__(256)
void softmax_causal(bf16* __restrict__ scores)
{
    __shared__ float red[8];
    const int row = blockIdx.x;           // b*2048 + q
    const int q   = row & 2047;
    bf16* srow = scores + (size_t)row * 2048;
    const int L = q + 1;
    const int tileEnd = ((q >> 8) + 1) << 8;   // 256-aligned, >= L
    const int t = threadIdx.x, lane = t & 63, wv = t >> 6;
    const int k0 = t * 8;
    const bool act = k0 < tileEnd;

    float f[8];
    if (act) {
        bf16x8 v = *(const bf16x8*)(srow + k0);
#pragma unroll
        for (int i = 0; i < 8; ++i)
            f[i] = (k0 + i < L) ? (float)v[i] : -INFINITY;
    } else {
#pragma unroll
        for (int i = 0; i < 8; ++i) f[i] = -INFINITY;
    }
    float m = f[0];
#pragma unroll
    for (int i = 1; i < 8; ++i) m = fmaxf(m, f[i]);
#pragma unroll
    for (int o = 32; o; o >>= 1) m = fmaxf(m, __shfl_xor(m, o));
    if (lane == 0) red[wv] = m;
    __syncthreads();
    m = fmaxf(fmaxf(red[0], red[1]), fmaxf(red[2], red[3]));

    float s = 0.f;
#pragma unroll
    for (int i = 0; i < 8; ++i) { f[i] = __expf(f[i] - m); s += f[i]; }
#pragma unroll
    for (int o = 32; o; o >>= 1) s += __shfl_xor(s, o);
    if (lane == 0) red[4 + wv] = s;
    __syncthreads();
    s = (red[4] + red[5]) + (red[6] + red[7]);
    const float inv = 1.f / s;

    if (act) {
        bf16x8 o8;
#pragma unroll
        for (int i = 0; i < 8; ++i) o8[i] = (bf16)(f[i] * inv);
        *(bf16x8*)(srow + k0) = o8;
    }
}

// ---------------------------------------------------------------------------
// Launch.  Workspace map (<= 102 MB):
//   Qb @0 (16MB) | Kb @16 (16MB) | Vt @32 (16MB)
//   scores bf16 @48 (32MB)  -- ALIASES Xqb/Xkb/Xvb @48/64/80 (dead after qkv)
//   Wt3 @96 (6MB)
// ---------------------------------------------------------------------------
extern "C" void kernel_launch(void* const* d_in, const int* in_sizes, int n_in,
                              void* d_out, int out_size, void* d_ws, size_t ws_size,
                              hipStream_t stream)
{
    const float* Xk = (const float*)d_in[0];
    const float* Xv = (const float*)d_in[1];
    const float* Xq = (const float*)d_in[2];
    const float* WK = (const float*)d_in[3];
    const float* WV = (const float*)d_in[4];
    const float* WQ = (const float*)d_in[5];

    float* outQ = (float*)d_out;                       // [4,2048,1024] f32
    float* outA = outQ + (size_t)8192 * 1024;          // [4,2048,1024] f32

    char* ws = (char*)d_ws;
    bf16*  Qb     = (bf16*)(ws);                       // 16MB
    bf16*  Kb     = (bf16*)(ws + (16ull << 20));       // 16MB
    bf16*  Vt     = (bf16*)(ws + (32ull << 20));       // 16MB  [1024][8192]
    bf16*  scores = (bf16*)(ws + (48ull << 20));       // 32MB  [4][2048][2048]
    bf16*  Xqb    = (bf16*)(ws + (48ull << 20));       // 16MB (aliases scores)
    bf16*  Xkb    = (bf16*)(ws + (64ull << 20));       // 16MB
    bf16*  Xvb    = (bf16*)(ws + (80ull << 20));       // 16MB
    bf16*  Wt3    = (bf16*)(ws + (96ull << 20));       // 6MB  [3][1024][1024]
    const float scale = 0.022097086912079608f;         // 1/sqrt(2048)

    hipFuncSetAttribute((const void*)gemm_qkv, hipFuncAttributeMaxDynamicSharedMemorySize, 49152);
    hipFuncSetAttribute((const void*)gemm_sc,  hipFuncAttributeMaxDynamicSharedMemorySize, 49152);
    hipFuncSetAttribute((const void*)gemm_pv,  hipFuncAttributeMaxDynamicSharedMemorySize, 49152);

    convert_x<<<dim3(12288), 256, 0, stream>>>(Xq, Xk, Xv, Xqb, Xkb, Xvb);

    transpose_w3<<<dim3(32, 32, 3), dim3(32, 8), 0, stream>>>(WQ, WK, WV, Wt3);

    gemm_qkv<<<dim3(12, 64), 512, 49152, stream>>>(
        Xqb, Xkb, Xvb, Wt3, outQ, Qb, Kb, Vt);

    gemm_sc<<<dim3(8, 16, 4), 512, 49152, stream>>>(Qb, Kb, scores, scale);

    softmax_causal<<<dim3(8192), 256, 0, stream>>>(scores);

    gemm_pv<<<dim3(256), 512, 49152, stream>>>(scores, Vt, outA);
}

// Round 12
// 172.404 us; speedup vs baseline: 1.0935x; 1.0935x over previous
//
#include <hip/hip_runtime.h>
#include <hip/hip_bf16.h>

typedef __bf16 bf16;
typedef bf16 bf16x8 __attribute__((ext_vector_type(8)));
typedef bf16 bf16x4 __attribute__((ext_vector_type(4)));
typedef float f32x4 __attribute__((ext_vector_type(4)));

#define BAR()   asm volatile("s_barrier" ::: "memory")
#define LGKM0() asm volatile("s_waitcnt lgkmcnt(0)" ::: "memory")
#define VMW4()  asm volatile("s_waitcnt vmcnt(4)" ::: "memory")
#define VMW3()  asm volatile("s_waitcnt vmcnt(3)" ::: "memory")
#define VMW2()  asm volatile("s_waitcnt vmcnt(2)" ::: "memory")
#define VMW0()  asm volatile("s_waitcnt vmcnt(0)" ::: "memory")

__device__ __forceinline__ void gload_lds16(const void* g, void* l) {
    __builtin_amdgcn_global_load_lds(
        (const __attribute__((address_space(1))) void*)g,
        (__attribute__((address_space(3))) void*)l, 16, 0, 0);
}

// ---------------------------------------------------------------------------
// 128x256 NT-GEMM core, BK=32, 8 waves (2M x 4N), 48KB double-buffered LDS.
// Verified r6/r8 schedule: stage tile t+1 (3 gloads), vmcnt(3), BAR,
// 8x ds_read_b128 (conflict-free via chunk XOR), 16 MFMA, lgkm0, BAR.
// Swizzle: LDS chunk c holds global chunk c ^ ((row>>1)&3); applied on the
// global source (linear gload_lds dest) and on ds_reads (both-sides rule).
// ---------------------------------------------------------------------------
__device__ __forceinline__
void gemm_core_bk32(const bf16* __restrict__ Ag, const bf16* __restrict__ Bg,
                    const int ldA, const int ldB, const int NT,
                    char* smem, f32x4 (&acc)[4][4])
{
    const int t    = threadIdx.x;          // 0..511
    const int lane = t & 63;
    const int wid  = t >> 6;
    const int wrow = wid >> 2;
    const int wcol = wid & 3;
    const int rl   = lane & 15;
    const int hi   = lane >> 4;
    const int ko   = ((hi ^ ((rl >> 1) & 3)) << 4);

    const int arow = t >> 2;
    const int sch  = (t & 3) ^ ((t >> 3) & 3);
    const bf16* pA  = Ag + (long long)arow * ldA + sch * 8;
    const bf16* pB0 = Bg + (long long)arow * ldB + sch * 8;
    const bf16* pB1 = pB0 + 128ll * ldB;
    char* uw = smem + (t & ~63) * 16;

#define STG32(tt) { char* db = uw + ((tt) & 1) * 24576; const int kk = (tt) * 32; \
    gload_lds16(pA  + kk, db); \
    gload_lds16(pB0 + kk, db + 8192); \
    gload_lds16(pB1 + kk, db + 16384); }

    STG32(0);
    for (int tt = 0; tt < NT; ++tt) {
        if (tt + 1 < NT) {
            STG32(tt + 1);
            VMW3();
        } else {
            VMW0();
        }
        BAR();
        const char* aB = smem + (tt & 1) * 24576;
        const char* bB = aB + 8192;
        bf16x8 af[4], bfr[4];
#pragma unroll
        for (int m = 0; m < 4; ++m)
            af[m]  = *(const bf16x8*)(aB + (wrow * 64 + m * 16 + rl) * 64 + ko);
#pragma unroll
        for (int n = 0; n < 4; ++n)
            bfr[n] = *(const bf16x8*)(bB + (wcol * 64 + n * 16 + rl) * 64 + ko);
        __builtin_amdgcn_s_setprio(1);
#pragma unroll
        for (int m = 0; m < 4; ++m)
#pragma unroll
            for (int n = 0; n < 4; ++n)
                acc[m][n] = __builtin_amdgcn_mfma_f32_16x16x32_bf16(
                                af[m], bfr[n], acc[m][n], 0, 0, 0);
        __builtin_amdgcn_s_setprio(0);
        LGKM0();
        BAR();
    }
#undef STG32
}

// ---------------------------------------------------------------------------
// af32 core: A f32 in global, reg-staged with TWO-TILE-AHEAD prefetch
// (alternating reg sets, static parity via unroll-by-2).  NT even.
// ---------------------------------------------------------------------------
__device__ __forceinline__
void gemm_core_af32(const float* __restrict__ Ag, const bf16* __restrict__ Bg,
                    const int ldA, const int ldB, const int NT,
                    char* smem, f32x4 (&acc)[4][4])
{
    const int t    = threadIdx.x;
    const int lane = t & 63;
    const int wid  = t >> 6;
    const int wrow = wid >> 2;
    const int wcol = wid & 3;
    const int rl   = lane & 15;
    const int hi   = lane >> 4;
    const int ko   = ((hi ^ ((rl >> 1) & 3)) << 4);

    const int arow = t >> 2;               // 0..127
    const int g    = t & 3;                // 16B-bf16 chunk (8 elems)
    const float* pAf = Ag + (long long)arow * ldA + g * 8;
    const int aoff = arow * 64 + ((g ^ ((arow >> 1) & 3)) << 4);  // swz LDS dest

    const int sch  = (t & 3) ^ ((t >> 3) & 3);
    const bf16* pB0 = Bg + (long long)arow * ldB + sch * 8;
    const bf16* pB1 = pB0 + 128ll * ldB;
    char* uw = smem + (t & ~63) * 16;

    float4 a0_0, a1_0;     // reg set parity 0
    float4 a0_1, a1_1;     // reg set parity 1

#define LDA_(s0_, s1_, tt) { const float* s_ = pAf + (tt) * 32; \
    s0_ = *(const float4*)s_; s1_ = *(const float4*)(s_ + 4); }
#define WRA_(s0_, s1_, tt) { bf16x8 vv; \
    vv[0]=(bf16)s0_.x; vv[1]=(bf16)s0_.y; vv[2]=(bf16)s0_.z; vv[3]=(bf16)s0_.w; \
    vv[4]=(bf16)s1_.x; vv[5]=(bf16)s1_.y; vv[6]=(bf16)s1_.z; vv[7]=(bf16)s1_.w; \
    *(bf16x8*)(smem + ((tt) & 1) * 24576 + aoff) = vv; }
#define STG_B(tt) { char* db = uw + ((tt) & 1) * 24576 + 8192; const int kk = (tt) * 32; \
    gload_lds16(pB0 + kk, db); gload_lds16(pB1 + kk, db + 8192); }

    LDA_(a0_0, a1_0, 0);
    STG_B(0);
    LDA_(a0_1, a1_1, 1);
    VMW4();
    WRA_(a0_0, a1_0, 0);
    LGKM0();

#define AITER(tt, sL0, sL1, sW0, sW1) { \
    const bool hasL = (tt) + 2 < NT, hasB = (tt) + 1 < NT; \
    if (hasL) LDA_(sL0, sL1, (tt) + 2); \
    if (hasB) STG_B((tt) + 1); \
    if (hasL)      VMW4(); \
    else if (hasB) VMW2(); \
    else           VMW0(); \
    BAR(); \
    const char* aB = smem + ((tt) & 1) * 24576; \
    const char* bB = aB + 8192; \
    bf16x8 af[4], bfr[4]; \
    _Pragma("unroll") \
    for (int m = 0; m < 4; ++m) \
        af[m]  = *(const bf16x8*)(aB + (wrow * 64 + m * 16 + rl) * 64 + ko); \
    _Pragma("unroll") \
    for (int n = 0; n < 4; ++n) \
        bfr[n] = *(const bf16x8*)(bB + (wcol * 64 + n * 16 + rl) * 64 + ko); \
    __builtin_amdgcn_s_setprio(1); \
    _Pragma("unroll") \
    for (int m = 0; m < 4; ++m) \
        _Pragma("unroll") \
        for (int n = 0; n < 4; ++n) \
            acc[m][n] = __builtin_amdgcn_mfma_f32_16x16x32_bf16( \
                            af[m], bfr[n], acc[m][n], 0, 0, 0); \
    __builtin_amdgcn_s_setprio(0); \
    if (hasB) WRA_(sW0, sW1, (tt) + 1); \
    LGKM0(); \
    BAR(); }

    for (int tt = 0; tt < NT; tt += 2) {
        AITER(tt,     a0_0, a1_0, a0_1, a1_1);
        AITER(tt + 1, a0_1, a1_1, a0_0, a1_0);
    }
#undef AITER
#undef LDA_
#undef WRA_
#undef STG_B
}

// ---------------------------------------------------------------------------
// Merged QKV projections, 128x256 tiles: grid (12, 64), XCD-remapped.
// A read directly as f32 (conversion fused).  mat==2 (V): LDS transpose.
// ---------------------------------------------------------------------------
__global__ __launch_bounds__(512, 4)
void gemm_qkv(const float* __restrict__ Xq, const float* __restrict__ Xk,
              const float* __restrict__ Xv,
              const bf16* __restrict__ Wt3,
              float* __restrict__ outQ, bf16* __restrict__ Qb,
              bf16* __restrict__ Kb, bf16* __restrict__ Vt)
{
    extern __shared__ char smem[];
    const int id0 = blockIdx.x + 12 * blockIdx.y;
    const int T   = (id0 & 7) * 96 + (id0 >> 3);
    const int bxn = T % 12, byn = T / 12;
    const int mat = bxn >> 2, nc = bxn & 3;

    const float* A = (mat == 0 ? Xq : mat == 1 ? Xk : Xv) + (long long)byn * 128 * 1024;
    const bf16* B = Wt3 + (long long)mat * 1024 * 1024 + (long long)nc * 256 * 1024;
    f32x4 acc[4][4] = {};
    gemm_core_af32(A, B, 1024, 1024, 32, smem, acc);

    const int t = threadIdx.x, lane = t & 63, wid = t >> 6;
    const int wr = (wid >> 2) * 64, wc = (wid & 3) * 64;
    const int rl = lane & 15, rg4 = (lane >> 4) * 4;

    if (mat != 2) {
#pragma unroll
        for (int m = 0; m < 4; ++m)
#pragma unroll
            for (int n = 0; n < 4; ++n)
#pragma unroll
                for (int j = 0; j < 4; ++j) {
                    const int row = byn * 128 + wr + m * 16 + rg4 + j;
                    const int col = nc * 256 + wc + n * 16 + rl;
                    const float v = acc[m][n][j];
                    if (mat == 0) { outQ[(long long)row * 1024 + col] = v;
                                    Qb[(long long)row * 1024 + col] = (bf16)v; }
                    else Kb[(long long)row * 1024 + col] = (bf16)v;
                }
    } else {
        // V: transpose via LDS (two 128-col halves; swizzled [128][128] bf16)
        char* lT = smem;
#pragma unroll
        for (int h = 0; h < 2; ++h) {
            BAR();
            if ((wc >> 7) == h) {
#pragma unroll
                for (int m = 0; m < 4; ++m)
#pragma unroll
                    for (int n = 0; n < 4; ++n) {
                        const int cp = (wc & 127) + n * 16 + rl;      // 0..127
                        const int rb = wr + m * 16 + rg4;             // 0..124
                        bf16x4 v;
                        v[0] = (bf16)acc[m][n][0]; v[1] = (bf16)acc[m][n][1];
                        v[2] = (bf16)acc[m][n][2]; v[3] = (bf16)acc[m][n][3];
                        *(bf16x4*)(lT + cp * 256 + ((rb * 2) ^ ((cp & 7) << 4))) = v;
                    }
            }
            BAR();
            const int c2 = t >> 2;
#pragma unroll
            for (int it = 0; it < 4; ++it) {
                const int q = (t & 3) + it * 4;                       // 0..15
                bf16x8 v = *(const bf16x8*)(lT + c2 * 256 + ((q << 4) ^ ((c2 & 7) << 4)));
                *(bf16x8*)(Vt + (long long)(nc * 256 + h * 128 + c2) * 8192
                              + byn * 128 + q * 8) = v;
            }
        }
    }
}

// ---------------------------------------------------------------------------
// QK^T causal, 128x256 tiles: grid (8, 16, 4); skip fully-masked tiles.
// Writes bf16 scores (ld 2048).
// ---------------------------------------------------------------------------
__global__ __launch_bounds__(512, 4)
void gemm_sc(const bf16* __restrict__ Qb, const bf16* __restrict__ Kb,
             bf16* __restrict__ scores, float scale)
{
    if (2 * blockIdx.x > blockIdx.y) return;
    extern __shared__ char smem[];
    const int bx = blockIdx.x, by = blockIdx.y, bz = blockIdx.z;
    const long long boff = (long long)bz * 2048 * 1024;
    f32x4 acc[4][4] = {};
    gemm_core_bk32(Qb + boff + (long long)by * 128 * 1024,
                   Kb + boff + (long long)bx * 256 * 1024, 1024, 1024, 32, smem, acc);

    const int t = threadIdx.x, lane = t & 63, wid = t >> 6;
    const int wr = (wid >> 2) * 64, wc = (wid & 3) * 64;
    const int rl = lane & 15, rg4 = (lane >> 4) * 4;
    bf16* Cb = scores + (long long)bz * 2048 * 2048;
#pragma unroll
    for (int m = 0; m < 4; ++m)
#pragma unroll
        for (int n = 0; n < 4; ++n)
#pragma unroll
            for (int j = 0; j < 4; ++j) {
                const int row = by * 128 + wr + m * 16 + rg4 + j;
                const int col = bx * 256 + wc + n * 16 + rl;
                Cb[(long long)row * 2048 + col] = (bf16)(acc[m][n][j] * scale);
            }
}

// ---------------------------------------------------------------------------
// PV with split-K load balancing.  Work units (per (bz,bx) pair): by<8 whole
// (NT=(by+1)*4 slots); by>=8 split into 2 K-halves (<=32 slots each).
// 24 units, descending cost; grid 384 with snake mapping (G<256: heavy
// ranks first; G>=256: lightest last) so CU pair-sums stay near uniform.
// ci=1 halves write partials (16MB, aliases Qb which is dead after sc);
// reduce_pv adds them into outA.
// ---------------------------------------------------------------------------
__constant__ int PV_BY[24] = {15,15,7,14,14,13,13,6,12,12,11,11,5,10,10,9,9,4,8,8,3,2,1,0};
__constant__ int PV_K0[24] = { 0,32,0, 0,30, 0,28,0, 0,26, 0,24,0, 0,22,0,20,0,0,18,0,0,0,0};
__constant__ int PV_NS[24] = {32,32,32,30,30,28,28,28,26,26,24,24,24,22,22,20,20,20,18,18,16,12,8,4};
__constant__ int PV_PR[24] = { 0, 1,0, 0, 1, 0, 1,0, 0, 1, 0, 1,0, 0, 1,0, 1,0,0, 1,0,0,0,0};

__global__ __launch_bounds__(512, 4)
void gemm_pv(const bf16* __restrict__ P, const bf16* __restrict__ Vt,
             float* __restrict__ outA, float* __restrict__ part)
{
    extern __shared__ char smem[];
    const int G = blockIdx.x;                          // 0..383
    const int u = (G < 256) ? (G >> 4) : (23 - ((G - 256) >> 4));
    const int p = G & 15;
    const int bz = p >> 2, bx = p & 3;
    const int by = PV_BY[u];
    const int k0 = PV_K0[u] * 32;                      // bf16 elems
    const int ns = PV_NS[u];
    const int pr = PV_PR[u];

    f32x4 acc[4][4] = {};
    gemm_core_bk32(P + (long long)bz * 2048 * 2048 + (long long)by * 128 * 2048 + k0,
                   Vt + (long long)bx * 256 * 8192 + (long long)bz * 2048 + k0,
                   2048, 8192, ns, smem, acc);

    const int t = threadIdx.x, lane = t & 63, wid = t >> 6;
    const int wr = (wid >> 2) * 64, wc = (wid & 3) * 64;
    const int rl = lane & 15, rg4 = (lane >> 4) * 4;

    if (!pr) {
        float* Cb = outA + (long long)bz * 2048 * 1024;
#pragma unroll
        for (int m = 0; m < 4; ++m)
#pragma unroll
            for (int n = 0; n < 4; ++n)
#pragma unroll
                for (int j = 0; j < 4; ++j) {
                    const int row = by * 128 + wr + m * 16 + rg4 + j;
                    const int col = bx * 256 + wc + n * 16 + rl;
                    Cb[(long long)row * 1024 + col] = acc[m][n][j];
                }
    } else {
        const int pi = ((by - 8) << 4) + p;            // 0..127
        float* Pp = part + (long long)pi * 32768;      // local [128][256] f32
#pragma unroll
        for (int m = 0; m < 4; ++m)
#pragma unroll
            for (int n = 0; n < 4; ++n)
#pragma unroll
                for (int j = 0; j < 4; ++j) {
                    const int r = wr + m * 16 + rg4 + j;
                    const int c = wc + n * 16 + rl;
                    Pp[r * 256 + c] = acc[m][n][j];
                }
    }
}

__global__ __launch_bounds__(256)
void reduce_pv(const float* __restrict__ part, float* __restrict__ outA)
{
    const int b  = blockIdx.x;            // 0..2047
    const int pi = b >> 4;                // tile 0..127
    const int sg = b & 15;
    const int by = (pi >> 4) + 8, bz = (pi >> 2) & 3, bx = pi & 3;
    const int e  = sg * 2048 + threadIdx.x * 8;        // 0..32760
    const int r  = e >> 8, c = e & 255;
    const float* src = part + (long long)pi * 32768 + e;
    float* dst = outA + (long long)bz * 2048 * 1024
               + (long long)(by * 128 + r) * 1024 + bx * 256 + c;
    float4 a0 = *(const float4*)src, a1 = *(const float4*)(src + 4);
    float4 d0 = *(const float4*)dst, d1 = *(const float4*)(dst + 4);
    d0.x += a0.x; d0.y += a0.y; d0.z += a0.z; d0.w += a0.w;
    d1.x += a1.x; d1.y += a1.y; d1.z += a1.z; d1.w += a1.w;
    *(float4*)dst = d0; *(float4*)(dst + 4) = d1;
}

// ---------------------------------------------------------------------------
// Transpose-convert all three W into contiguous Wt3[mat][n][k]: grid (32,32,3).
// ---------------------------------------------------------------------------
__global__ __launch_bounds__(256)
void transpose_w3(const float* __restrict__ W0, const float* __restrict__ W1,
                  const float* __restrict__ W2, bf16* __restrict__ Wt3)
{
    __shared__ float tile[32][33];
    const int w = blockIdx.z;
    const float* W = w == 0 ? W0 : w == 1 ? W1 : W2;
    bf16* Wt = Wt3 + (size_t)w * 1024 * 1024;
    const int bx = blockIdx.x * 32;
    const int by = blockIdx.y * 32;
    const int tx = threadIdx.x;
    const int ty = threadIdx.y;
    for (int i = ty; i < 32; i += 8)
        tile[i][tx] = W[(size_t)(by + i) * 1024 + bx + tx];
    __syncthreads();
    for (int i = ty; i < 32; i += 8)
        Wt[(size_t)(bx + i) * 1024 + by + tx] = (bf16)tile[tx][i];
}

// ---------------------------------------------------------------------------
// Causal row softmax over bf16 scores, in place, pure register pass.
// ---------------------------------------------------------------------------
__global__ __launch_bounds__(256)
void softmax_causal(bf16* __restrict__ scores)
{
    __shared__ float red[8];
    const int row = blockIdx.x;           // b*2048 + q
    const int q   = row & 2047;
    bf16* srow = scores + (size_t)row * 2048;
    const int L = q + 1;
    const int tileEnd = ((q >> 8) + 1) << 8;   // 256-aligned, >= L
    const int t = threadIdx.x, lane = t & 63, wv = t >> 6;
    const int k0 = t * 8;
    const bool act = k0 < tileEnd;

    float f[8];
    if (act) {
        bf16x8 v = *(const bf16x8*)(srow + k0);
#pragma unroll
        for (int i = 0; i < 8; ++i)
            f[i] = (k0 + i < L) ? (float)v[i] : -INFINITY;
    } else {
#pragma unroll
        for (int i = 0; i < 8; ++i) f[i] = -INFINITY;
    }
    float m = f[0];
#pragma unroll
    for (int i = 1; i < 8; ++i) m = fmaxf(m, f[i]);
#pragma unroll
    for (int o = 32; o; o >>= 1) m = fmaxf(m, __shfl_xor(m, o));
    if (lane == 0) red[wv] = m;
    __syncthreads();
    m = fmaxf(fmaxf(red[0], red[1]), fmaxf(red[2], red[3]));

    float s = 0.f;
#pragma unroll
    for (int i = 0; i < 8; ++i) { f[i] = __expf(f[i] - m); s += f[i]; }
#pragma unroll
    for (int o = 32; o; o >>= 1) s += __shfl_xor(s, o);
    if (lane == 0) red[4 + wv] = s;
    __syncthreads();
    s = (red[4] + red[5]) + (red[6] + red[7]);
    const float inv = 1.f / s;

    if (act) {
        bf16x8 o8;
#pragma unroll
        for (int i = 0; i < 8; ++i) o8[i] = (bf16)(f[i] * inv);
        *(bf16x8*)(srow + k0) = o8;
    }
}

// ---------------------------------------------------------------------------
// Launch.  Workspace map:
//   Qb @0 (16MB, dead after sc -> reused as PV partial buffer)
//   Kb @16 (16MB) | Vt @32 (16MB) | scores bf16 @48 (32MB) | Wt3 @80 (6MB)
// ---------------------------------------------------------------------------
extern "C" void kernel_launch(void* const* d_in, const int* in_sizes, int n_in,
                              void* d_out, int out_size, void* d_ws, size_t ws_size,
                              hipStream_t stream)
{
    const float* Xk = (const float*)d_in[0];
    const float* Xv = (const float*)d_in[1];
    const float* Xq = (const float*)d_in[2];
    const float* WK = (const float*)d_in[3];
    const float* WV = (const float*)d_in[4];
    const float* WQ = (const float*)d_in[5];

    float* outQ = (float*)d_out;                       // [4,2048,1024] f32
    float* outA = outQ + (size_t)8192 * 1024;          // [4,2048,1024] f32

    char* ws = (char*)d_ws;
    bf16*  Qb     = (bf16*)(ws);                       // 16MB
    bf16*  Kb     = (bf16*)(ws + (16ull << 20));       // 16MB
    bf16*  Vt     = (bf16*)(ws + (32ull << 20));       // 16MB  [1024][8192]
    bf16*  scores = (bf16*)(ws + (48ull << 20));       // 32MB  [4][2048][2048]
    bf16*  Wt3    = (bf16*)(ws + (80ull << 20));       // 6MB   [3][1024][1024]
    float* part   = (float*)(ws);                      // 16MB, aliases Qb
    const float scale = 0.022097086912079608f;         // 1/sqrt(2048)

    hipFuncSetAttribute((const void*)gemm_qkv, hipFuncAttributeMaxDynamicSharedMemorySize, 49152);
    hipFuncSetAttribute((const void*)gemm_sc,  hipFuncAttributeMaxDynamicSharedMemorySize, 49152);
    hipFuncSetAttribute((const void*)gemm_pv,  hipFuncAttributeMaxDynamicSharedMemorySize, 49152);

    transpose_w3<<<dim3(32, 32, 3), dim3(32, 8), 0, stream>>>(WQ, WK, WV, Wt3);

    gemm_qkv<<<dim3(12, 64), 512, 49152, stream>>>(
        Xq, Xk, Xv, Wt3, outQ, Qb, Kb, Vt);

    gemm_sc<<<dim3(8, 16, 4), 512, 49152, stream>>>(Qb, Kb, scores, scale);

    softmax_causal<<<dim3(8192), 256, 0, stream>>>(scores);

    gemm_pv<<<dim3(384), 512, 49152, stream>>>(scores, Vt, outA, part);

    reduce_pv<<<dim3(2048), 256, 0, stream>>>(part, outA);
}

// Round 13
// 167.974 us; speedup vs baseline: 1.1223x; 1.0264x over previous
//
#include <hip/hip_runtime.h>
#include <hip/hip_bf16.h>

typedef __bf16 bf16;
typedef bf16 bf16x8 __attribute__((ext_vector_type(8)));
typedef bf16 bf16x4 __attribute__((ext_vector_type(4)));
typedef float f32x4 __attribute__((ext_vector_type(4)));

#define BAR()   asm volatile("s_barrier" ::: "memory")
#define LGKM0() asm volatile("s_waitcnt lgkmcnt(0)" ::: "memory")
#define VMW4()  asm volatile("s_waitcnt vmcnt(4)" ::: "memory")
#define VMW3()  asm volatile("s_waitcnt vmcnt(3)" ::: "memory")
#define VMW2()  asm volatile("s_waitcnt vmcnt(2)" ::: "memory")
#define VMW0()  asm volatile("s_waitcnt vmcnt(0)" ::: "memory")

__device__ __forceinline__ void gload_lds16(const void* g, void* l) {
    __builtin_amdgcn_global_load_lds(
        (const __attribute__((address_space(1))) void*)g,
        (__attribute__((address_space(3))) void*)l, 16, 0, 0);
}

// ---------------------------------------------------------------------------
// 128x256 NT-GEMM core, BK=32, 8 waves (2M x 4N), 48KB double-buffered LDS.
// Verified r6/r8 schedule: stage tile t+1 (3 gloads), vmcnt(3), BAR,
// 8x ds_read_b128 (conflict-free via chunk XOR), 16 MFMA, lgkm0, BAR.
// Swizzle: LDS chunk c holds global chunk c ^ ((row>>1)&3); applied on the
// global source (linear gload_lds dest) and on ds_reads (both-sides rule).
// ---------------------------------------------------------------------------
__device__ __forceinline__
void gemm_core_bk32(const bf16* __restrict__ Ag, const bf16* __restrict__ Bg,
                    const int ldA, const int ldB, const int NT,
                    char* smem, f32x4 (&acc)[4][4])
{
    const int t    = threadIdx.x;          // 0..511
    const int lane = t & 63;
    const int wid  = t >> 6;
    const int wrow = wid >> 2;
    const int wcol = wid & 3;
    const int rl   = lane & 15;
    const int hi   = lane >> 4;
    const int ko   = ((hi ^ ((rl >> 1) & 3)) << 4);

    const int arow = t >> 2;
    const int sch  = (t & 3) ^ ((t >> 3) & 3);
    const bf16* pA  = Ag + (long long)arow * ldA + sch * 8;
    const bf16* pB0 = Bg + (long long)arow * ldB + sch * 8;
    const bf16* pB1 = pB0 + 128ll * ldB;
    char* uw = smem + (t & ~63) * 16;

#define STG32(tt) { char* db = uw + ((tt) & 1) * 24576; const int kk = (tt) * 32; \
    gload_lds16(pA  + kk, db); \
    gload_lds16(pB0 + kk, db + 8192); \
    gload_lds16(pB1 + kk, db + 16384); }

    STG32(0);
    for (int tt = 0; tt < NT; ++tt) {
        if (tt + 1 < NT) {
            STG32(tt + 1);
            VMW3();
        } else {
            VMW0();
        }
        BAR();
        const char* aB = smem + (tt & 1) * 24576;
        const char* bB = aB + 8192;
        bf16x8 af[4], bfr[4];
#pragma unroll
        for (int m = 0; m < 4; ++m)
            af[m]  = *(const bf16x8*)(aB + (wrow * 64 + m * 16 + rl) * 64 + ko);
#pragma unroll
        for (int n = 0; n < 4; ++n)
            bfr[n] = *(const bf16x8*)(bB + (wcol * 64 + n * 16 + rl) * 64 + ko);
        __builtin_amdgcn_s_setprio(1);
#pragma unroll
        for (int m = 0; m < 4; ++m)
#pragma unroll
            for (int n = 0; n < 4; ++n)
                acc[m][n] = __builtin_amdgcn_mfma_f32_16x16x32_bf16(
                                af[m], bfr[n], acc[m][n], 0, 0, 0);
        __builtin_amdgcn_s_setprio(0);
        LGKM0();
        BAR();
    }
#undef STG32
}

// ---------------------------------------------------------------------------
// af32 core: A f32 in global, reg-staged with TWO-TILE-AHEAD prefetch
// (alternating reg sets, static parity via unroll-by-2).  NT even.
// ---------------------------------------------------------------------------
__device__ __forceinline__
void gemm_core_af32(const float* __restrict__ Ag, const bf16* __restrict__ Bg,
                    const int ldA, const int ldB, const int NT,
                    char* smem, f32x4 (&acc)[4][4])
{
    const int t    = threadIdx.x;
    const int lane = t & 63;
    const int wid  = t >> 6;
    const int wrow = wid >> 2;
    const int wcol = wid & 3;
    const int rl   = lane & 15;
    const int hi   = lane >> 4;
    const int ko   = ((hi ^ ((rl >> 1) & 3)) << 4);

    const int arow = t >> 2;               // 0..127
    const int g    = t & 3;                // 16B-bf16 chunk (8 elems)
    const float* pAf = Ag + (long long)arow * ldA + g * 8;
    const int aoff = arow * 64 + ((g ^ ((arow >> 1) & 3)) << 4);  // swz LDS dest

    const int sch  = (t & 3) ^ ((t >> 3) & 3);
    const bf16* pB0 = Bg + (long long)arow * ldB + sch * 8;
    const bf16* pB1 = pB0 + 128ll * ldB;
    char* uw = smem + (t & ~63) * 16;

    float4 a0_0, a1_0;     // reg set parity 0
    float4 a0_1, a1_1;     // reg set parity 1

#define LDA_(s0_, s1_, tt) { const float* s_ = pAf + (tt) * 32; \
    s0_ = *(const float4*)s_; s1_ = *(const float4*)(s_ + 4); }
#define WRA_(s0_, s1_, tt) { bf16x8 vv; \
    vv[0]=(bf16)s0_.x; vv[1]=(bf16)s0_.y; vv[2]=(bf16)s0_.z; vv[3]=(bf16)s0_.w; \
    vv[4]=(bf16)s1_.x; vv[5]=(bf16)s1_.y; vv[6]=(bf16)s1_.z; vv[7]=(bf16)s1_.w; \
    *(bf16x8*)(smem + ((tt) & 1) * 24576 + aoff) = vv; }
#define STG_B(tt) { char* db = uw + ((tt) & 1) * 24576 + 8192; const int kk = (tt) * 32; \
    gload_lds16(pB0 + kk, db); gload_lds16(pB1 + kk, db + 8192); }

    LDA_(a0_0, a1_0, 0);
    STG_B(0);
    LDA_(a0_1, a1_1, 1);
    VMW4();
    WRA_(a0_0, a1_0, 0);
    LGKM0();

#define AITER(tt, sL0, sL1, sW0, sW1) { \
    const bool hasL = (tt) + 2 < NT, hasB = (tt) + 1 < NT; \
    if (hasL) LDA_(sL0, sL1, (tt) + 2); \
    if (hasB) STG_B((tt) + 1); \
    if (hasL)      VMW4(); \
    else if (hasB) VMW2(); \
    else           VMW0(); \
    BAR(); \
    const char* aB = smem + ((tt) & 1) * 24576; \
    const char* bB = aB + 8192; \
    bf16x8 af[4], bfr[4]; \
    _Pragma("unroll") \
    for (int m = 0; m < 4; ++m) \
        af[m]  = *(const bf16x8*)(aB + (wrow * 64 + m * 16 + rl) * 64 + ko); \
    _Pragma("unroll") \
    for (int n = 0; n < 4; ++n) \
        bfr[n] = *(const bf16x8*)(bB + (wcol * 64 + n * 16 + rl) * 64 + ko); \
    __builtin_amdgcn_s_setprio(1); \
    _Pragma("unroll") \
    for (int m = 0; m < 4; ++m) \
        _Pragma("unroll") \
        for (int n = 0; n < 4; ++n) \
            acc[m][n] = __builtin_amdgcn_mfma_f32_16x16x32_bf16( \
                            af[m], bfr[n], acc[m][n], 0, 0, 0); \
    __builtin_amdgcn_s_setprio(0); \
    if (hasB) WRA_(sW0, sW1, (tt) + 1); \
    LGKM0(); \
    BAR(); }

    for (int tt = 0; tt < NT; tt += 2) {
        AITER(tt,     a0_0, a1_0, a0_1, a1_1);
        AITER(tt + 1, a0_1, a1_1, a0_0, a1_0);
    }
#undef AITER
#undef LDA_
#undef WRA_
#undef STG_B
}

// ---------------------------------------------------------------------------
// Merged QKV projections, 128x256 tiles: grid (12, 64), XCD-remapped.
// A read directly as f32 (conversion fused).  mat==2 (V): LDS transpose.
// ---------------------------------------------------------------------------
__global__ __launch_bounds__(512, 4)
void gemm_qkv(const float* __restrict__ Xq, const float* __restrict__ Xk,
              const float* __restrict__ Xv,
              const bf16* __restrict__ Wt3,
              float* __restrict__ outQ, bf16* __restrict__ Qb,
              bf16* __restrict__ Kb, bf16* __restrict__ Vt)
{
    extern __shared__ char smem[];
    const int id0 = blockIdx.x + 12 * blockIdx.y;
    const int T   = (id0 & 7) * 96 + (id0 >> 3);
    const int bxn = T % 12, byn = T / 12;
    const int mat = bxn >> 2, nc = bxn & 3;

    const float* A = (mat == 0 ? Xq : mat == 1 ? Xk : Xv) + (long long)byn * 128 * 1024;
    const bf16* B = Wt3 + (long long)mat * 1024 * 1024 + (long long)nc * 256 * 1024;
    f32x4 acc[4][4] = {};
    gemm_core_af32(A, B, 1024, 1024, 32, smem, acc);

    const int t = threadIdx.x, lane = t & 63, wid = t >> 6;
    const int wr = (wid >> 2) * 64, wc = (wid & 3) * 64;
    const int rl = lane & 15, rg4 = (lane >> 4) * 4;

    if (mat != 2) {
#pragma unroll
        for (int m = 0; m < 4; ++m)
#pragma unroll
            for (int n = 0; n < 4; ++n)
#pragma unroll
                for (int j = 0; j < 4; ++j) {
                    const int row = byn * 128 + wr + m * 16 + rg4 + j;
                    const int col = nc * 256 + wc + n * 16 + rl;
                    const float v = acc[m][n][j];
                    if (mat == 0) { outQ[(long long)row * 1024 + col] = v;
                                    Qb[(long long)row * 1024 + col] = (bf16)v; }
                    else Kb[(long long)row * 1024 + col] = (bf16)v;
                }
    } else {
        // V: transpose via LDS (two 128-col halves; swizzled [128][128] bf16)
        char* lT = smem;
#pragma unroll
        for (int h = 0; h < 2; ++h) {
            BAR();
            if ((wc >> 7) == h) {
#pragma unroll
                for (int m = 0; m < 4; ++m)
#pragma unroll
                    for (int n = 0; n < 4; ++n) {
                        const int cp = (wc & 127) + n * 16 + rl;      // 0..127
                        const int rb = wr + m * 16 + rg4;             // 0..124
                        bf16x4 v;
                        v[0] = (bf16)acc[m][n][0]; v[1] = (bf16)acc[m][n][1];
                        v[2] = (bf16)acc[m][n][2]; v[3] = (bf16)acc[m][n][3];
                        *(bf16x4*)(lT + cp * 256 + ((rb * 2) ^ ((cp & 7) << 4))) = v;
                    }
            }
            BAR();
            const int c2 = t >> 2;
#pragma unroll
            for (int it = 0; it < 4; ++it) {
                const int q = (t & 3) + it * 4;                       // 0..15
                bf16x8 v = *(const bf16x8*)(lT + c2 * 256 + ((q << 4) ^ ((c2 & 7) << 4)));
                *(bf16x8*)(Vt + (long long)(nc * 256 + h * 128 + c2) * 8192
                              + byn * 128 + q * 8) = v;
            }
        }
    }
}

// ---------------------------------------------------------------------------
// QK^T causal, 128x256 tiles, COMPACT grid (72, 4): only active tiles
// (2*bx <= by) are launched.  Writes bf16 scores (ld 2048).
// ---------------------------------------------------------------------------
__constant__ int SC_BX[72] = {0,0,0,1,0,1,0,1,2,0,1,2,0,1,2,3,0,1,2,3,
                              0,1,2,3,4,0,1,2,3,4,0,1,2,3,4,5,0,1,2,3,4,5,
                              0,1,2,3,4,5,6,0,1,2,3,4,5,6,
                              0,1,2,3,4,5,6,7,0,1,2,3,4,5,6,7};
__constant__ int SC_BY[72] = {0,1,2,2,3,3,4,4,4,5,5,5,6,6,6,6,7,7,7,7,
                              8,8,8,8,8,9,9,9,9,9,10,10,10,10,10,10,11,11,11,11,11,11,
                              12,12,12,12,12,12,12,13,13,13,13,13,13,13,
                              14,14,14,14,14,14,14,14,15,15,15,15,15,15,15,15};

__global__ __launch_bounds__(512, 4)
void gemm_sc(const bf16* __restrict__ Qb, const bf16* __restrict__ Kb,
             bf16* __restrict__ scores, float scale)
{
    extern __shared__ char smem[];
    const int bx = SC_BX[blockIdx.x], by = SC_BY[blockIdx.x], bz = blockIdx.y;
    const long long boff = (long long)bz * 2048 * 1024;
    f32x4 acc[4][4] = {};
    gemm_core_bk32(Qb + boff + (long long)by * 128 * 1024,
                   Kb + boff + (long long)bx * 256 * 1024, 1024, 1024, 32, smem, acc);

    const int t = threadIdx.x, lane = t & 63, wid = t >> 6;
    const int wr = (wid >> 2) * 64, wc = (wid & 3) * 64;
    const int rl = lane & 15, rg4 = (lane >> 4) * 4;
    bf16* Cb = scores + (long long)bz * 2048 * 2048;
#pragma unroll
    for (int m = 0; m < 4; ++m)
#pragma unroll
        for (int n = 0; n < 4; ++n)
#pragma unroll
            for (int j = 0; j < 4; ++j) {
                const int row = by * 128 + wr + m * 16 + rg4 + j;
                const int col = bx * 256 + wc + n * 16 + rl;
                Cb[(long long)row * 2048 + col] = (bf16)(acc[m][n][j] * scale);
            }
}

// ---------------------------------------------------------------------------
// PV: 128x256 tiles, grid 256 -> (bz, bx 0..3, by 0..15 interleaved).
// A = P (bf16, ld 2048), B = Vt (ld 8192), NT = (by+1)*4 (K-limit).
// ---------------------------------------------------------------------------
__global__ __launch_bounds__(512, 4)
void gemm_pv(const bf16* __restrict__ P, const bf16* __restrict__ Vt,
             float* __restrict__ outA)
{
    extern __shared__ char smem[];
    const int F = blockIdx.x;
    const int bz = F & 3;
    const int bx = (F >> 2) & 3;
    const int byr = F >> 4;                       // 0..15
    const int by = (byr & 1) ? (byr >> 1) : (15 - (byr >> 1));
    f32x4 acc[4][4] = {};
    gemm_core_bk32(P + (long long)bz * 2048 * 2048 + (long long)by * 128 * 2048,
                   Vt + (long long)bx * 256 * 8192 + (long long)bz * 2048,
                   2048, 8192, (by + 1) * 4, smem, acc);

    const int t = threadIdx.x, lane = t & 63, wid = t >> 6;
    const int wr = (wid >> 2) * 64, wc = (wid & 3) * 64;
    const int rl = lane & 15, rg4 = (lane >> 4) * 4;
    float* Cb = outA + (long long)bz * 2048 * 1024;
#pragma unroll
    for (int m = 0; m < 4; ++m)
#pragma unroll
        for (int n = 0; n < 4; ++n)
#pragma unroll
            for (int j = 0; j < 4; ++j) {
                const int row = by * 128 + wr + m * 16 + rg4 + j;
                const int col = bx * 256 + wc + n * 16 + rl;
                Cb[(long long)row * 1024 + col] = acc[m][n][j];
            }
}

// ---------------------------------------------------------------------------
// Transpose-convert all three W into contiguous Wt3[mat][n][k]: grid (32,32,3).
// ---------------------------------------------------------------------------
__global__ __launch_bounds__(256)
void transpose_w3(const float* __restrict__ W0, const float* __restrict__ W1,
                  const float* __restrict__ W2, bf16* __restrict__ Wt3)
{
    __shared__ float tile[32][33];
    const int w = blockIdx.z;
    const float* W = w == 0 ? W0 : w == 1 ? W1 : W2;
    bf16* Wt = Wt3 + (size_t)w * 1024 * 1024;
    const int bx = blockIdx.x * 32;
    const int by = blockIdx.y * 32;
    const int tx = threadIdx.x;
    const int ty = threadIdx.y;
    for (int i = ty; i < 32; i += 8)
        tile[i][tx] = W[(size_t)(by + i) * 1024 + bx + tx];
    __syncthreads();
    for (int i = ty; i < 32; i += 8)
        Wt[(size_t)(bx + i) * 1024 + by + tx] = (bf16)tile[tx][i];
}

// ---------------------------------------------------------------------------
// Causal row softmax over bf16 scores, in place, pure register pass.
// ---------------------------------------------------------------------------
__global__ __launch_bounds__(256)
void softmax_causal(bf16* __restrict__ scores)
{
    __shared__ float red[8];
    const int row = blockIdx.x;           // b*2048 + q
    const int q   = row & 2047;
    bf16* srow = scores + (size_t)row * 2048;
    const int L = q + 1;
    const int tileEnd = ((q >> 8) + 1) << 8;   // 256-aligned, >= L
    const int t = threadIdx.x, lane = t & 63, wv = t >> 6;
    const int k0 = t * 8;
    const bool act = k0 < tileEnd;

    float f[8];
    if (act) {
        bf16x8 v = *(const bf16x8*)(srow + k0);
#pragma unroll
        for (int i = 0; i < 8; ++i)
            f[i] = (k0 + i < L) ? (float)v[i] : -INFINITY;
    } else {
#pragma unroll
        for (int i = 0; i < 8; ++i) f[i] = -INFINITY;
    }
    float m = f[0];
#pragma unroll
    for (int i = 1; i < 8; ++i) m = fmaxf(m, f[i]);
#pragma unroll
    for (int o = 32; o; o >>= 1) m = fmaxf(m, __shfl_xor(m, o));
    if (lane == 0) red[wv] = m;
    __syncthreads();
    m = fmaxf(fmaxf(red[0], red[1]), fmaxf(red[2], red[3]));

    float s = 0.f;
#pragma unroll
    for (int i = 0; i < 8; ++i) { f[i] = __expf(f[i] - m); s += f[i]; }
#pragma unroll
    for (int o = 32; o; o >>= 1) s += __shfl_xor(s, o);
    if (lane == 0) red[4 + wv] = s;
    __syncthreads();
    s = (red[4] + red[5]) + (red[6] + red[7]);
    const float inv = 1.f / s;

    if (act) {
        bf16x8 o8;
#pragma unroll
        for (int i = 0; i < 8; ++i) o8[i] = (bf16)(f[i] * inv);
        *(bf16x8*)(srow + k0) = o8;
    }
}

// ---------------------------------------------------------------------------
// Launch.  Workspace map:
//   Qb @0 (16MB) | Kb @16 (16MB) | Vt @32 (16MB)
//   scores bf16 @48 (32MB) | Wt3 @80 (6MB)
// ---------------------------------------------------------------------------
extern "C" void kernel_launch(void* const* d_in, const int* in_sizes, int n_in,
                              void* d_out, int out_size, void* d_ws, size_t ws_size,
                              hipStream_t stream)
{
    const float* Xk = (const float*)d_in[0];
    const float* Xv = (const float*)d_in[1];
    const float* Xq = (const float*)d_in[2];
    const float* WK = (const float*)d_in[3];
    const float* WV = (const float*)d_in[4];
    const float* WQ = (const float*)d_in[5];

    float* outQ = (float*)d_out;                       // [4,2048,1024] f32
    float* outA = outQ + (size_t)8192 * 1024;          // [4,2048,1024] f32

    char* ws = (char*)d_ws;
    bf16*  Qb     = (bf16*)(ws);                       // 16MB
    bf16*  Kb     = (bf16*)(ws + (16ull << 20));       // 16MB
    bf16*  Vt     = (bf16*)(ws + (32ull << 20));       // 16MB  [1024][8192]
    bf16*  scores = (bf16*)(ws + (48ull << 20));       // 32MB  [4][2048][2048]
    bf16*  Wt3    = (bf16*)(ws + (80ull << 20));       // 6MB   [3][1024][1024]
    const float scale = 0.022097086912079608f;         // 1/sqrt(2048)

    hipFuncSetAttribute((const void*)gemm_qkv, hipFuncAttributeMaxDynamicSharedMemorySize, 49152);
    hipFuncSetAttribute((const void*)gemm_sc,  hipFuncAttributeMaxDynamicSharedMemorySize, 49152);
    hipFuncSetAttribute((const void*)gemm_pv,  hipFuncAttributeMaxDynamicSharedMemorySize, 49152);

    transpose_w3<<<dim3(32, 32, 3), dim3(32, 8), 0, stream>>>(WQ, WK, WV, Wt3);

    gemm_qkv<<<dim3(12, 64), 512, 49152, stream>>>(
        Xq, Xk, Xv, Wt3, outQ, Qb, Kb, Vt);

    gemm_sc<<<dim3(72, 4), 512, 49152, stream>>>(Qb, Kb, scores, scale);

    softmax_causal<<<dim3(8192), 256, 0, stream>>>(scores);

    gemm_pv<<<dim3(256), 512, 49152, stream>>>(scores, Vt, outA);
}

// Round 14
// 158.577 us; speedup vs baseline: 1.1888x; 1.0593x over previous
//
#include <hip/hip_runtime.h>
#include <hip/hip_bf16.h>

typedef __bf16 bf16;
typedef bf16 bf16x8 __attribute__((ext_vector_type(8)));
typedef bf16 bf16x4 __attribute__((ext_vector_type(4)));
typedef float f32x4 __attribute__((ext_vector_type(4)));

#define BAR()   asm volatile("s_barrier" ::: "memory")
#define LGKM0() asm volatile("s_waitcnt lgkmcnt(0)" ::: "memory")
#define VMW4()  asm volatile("s_waitcnt vmcnt(4)" ::: "memory")
#define VMW3()  asm volatile("s_waitcnt vmcnt(3)" ::: "memory")
#define VMW2()  asm volatile("s_waitcnt vmcnt(2)" ::: "memory")
#define VMW0()  asm volatile("s_waitcnt vmcnt(0)" ::: "memory")

__device__ __forceinline__ void gload_lds16(const void* g, void* l) {
    __builtin_amdgcn_global_load_lds(
        (const __attribute__((address_space(1))) void*)g,
        (__attribute__((address_space(3))) void*)l, 16, 0, 0);
}

// ---------------------------------------------------------------------------
// 128x256 NT-GEMM core, BK=32, 8 waves (2M x 4N), 48KB double-buffered LDS.
// Verified r6/r8 schedule: stage tile t+1 (3 gloads), vmcnt(3), BAR,
// 8x ds_read_b128 (conflict-free via chunk XOR), 16 MFMA, lgkm0, BAR.
// Swizzle: LDS chunk c holds global chunk c ^ ((row>>1)&3); applied on the
// global source (linear gload_lds dest) and on ds_reads (both-sides rule).
// ---------------------------------------------------------------------------
__device__ __forceinline__
void gemm_core_bk32(const bf16* __restrict__ Ag, const bf16* __restrict__ Bg,
                    const int ldA, const int ldB, const int NT,
                    char* smem, f32x4 (&acc)[4][4])
{
    const int t    = threadIdx.x;          // 0..511
    const int lane = t & 63;
    const int wid  = t >> 6;
    const int wrow = wid >> 2;
    const int wcol = wid & 3;
    const int rl   = lane & 15;
    const int hi   = lane >> 4;
    const int ko   = ((hi ^ ((rl >> 1) & 3)) << 4);

    const int arow = t >> 2;
    const int sch  = (t & 3) ^ ((t >> 3) & 3);
    const bf16* pA  = Ag + (long long)arow * ldA + sch * 8;
    const bf16* pB0 = Bg + (long long)arow * ldB + sch * 8;
    const bf16* pB1 = pB0 + 128ll * ldB;
    char* uw = smem + (t & ~63) * 16;

#define STG32(tt) { char* db = uw + ((tt) & 1) * 24576; const int kk = (tt) * 32; \
    gload_lds16(pA  + kk, db); \
    gload_lds16(pB0 + kk, db + 8192); \
    gload_lds16(pB1 + kk, db + 16384); }

    STG32(0);
    for (int tt = 0; tt < NT; ++tt) {
        if (tt + 1 < NT) {
            STG32(tt + 1);
            VMW3();
        } else {
            VMW0();
        }
        BAR();
        const char* aB = smem + (tt & 1) * 24576;
        const char* bB = aB + 8192;
        bf16x8 af[4], bfr[4];
#pragma unroll
        for (int m = 0; m < 4; ++m)
            af[m]  = *(const bf16x8*)(aB + (wrow * 64 + m * 16 + rl) * 64 + ko);
#pragma unroll
        for (int n = 0; n < 4; ++n)
            bfr[n] = *(const bf16x8*)(bB + (wcol * 64 + n * 16 + rl) * 64 + ko);
        __builtin_amdgcn_s_setprio(1);
#pragma unroll
        for (int m = 0; m < 4; ++m)
#pragma unroll
            for (int n = 0; n < 4; ++n)
                acc[m][n] = __builtin_amdgcn_mfma_f32_16x16x32_bf16(
                                af[m], bfr[n], acc[m][n], 0, 0, 0);
        __builtin_amdgcn_s_setprio(0);
        LGKM0();
        BAR();
    }
#undef STG32
}

// ---------------------------------------------------------------------------
// af32 core: A f32 in global, reg-staged with TWO-TILE-AHEAD prefetch
// (alternating reg sets, static parity via unroll-by-2).  NT even.
// ---------------------------------------------------------------------------
__device__ __forceinline__
void gemm_core_af32(const float* __restrict__ Ag, const bf16* __restrict__ Bg,
                    const int ldA, const int ldB, const int NT,
                    char* smem, f32x4 (&acc)[4][4])
{
    const int t    = threadIdx.x;
    const int lane = t & 63;
    const int wid  = t >> 6;
    const int wrow = wid >> 2;
    const int wcol = wid & 3;
    const int rl   = lane & 15;
    const int hi   = lane >> 4;
    const int ko   = ((hi ^ ((rl >> 1) & 3)) << 4);

    const int arow = t >> 2;               // 0..127
    const int g    = t & 3;                // 16B-bf16 chunk (8 elems)
    const float* pAf = Ag + (long long)arow * ldA + g * 8;
    const int aoff = arow * 64 + ((g ^ ((arow >> 1) & 3)) << 4);  // swz LDS dest

    const int sch  = (t & 3) ^ ((t >> 3) & 3);
    const bf16* pB0 = Bg + (long long)arow * ldB + sch * 8;
    const bf16* pB1 = pB0 + 128ll * ldB;
    char* uw = smem + (t & ~63) * 16;

    float4 a0_0, a1_0;     // reg set parity 0
    float4 a0_1, a1_1;     // reg set parity 1

#define LDA_(s0_, s1_, tt) { const float* s_ = pAf + (tt) * 32; \
    s0_ = *(const float4*)s_; s1_ = *(const float4*)(s_ + 4); }
#define WRA_(s0_, s1_, tt) { bf16x8 vv; \
    vv[0]=(bf16)s0_.x; vv[1]=(bf16)s0_.y; vv[2]=(bf16)s0_.z; vv[3]=(bf16)s0_.w; \
    vv[4]=(bf16)s1_.x; vv[5]=(bf16)s1_.y; vv[6]=(bf16)s1_.z; vv[7]=(bf16)s1_.w; \
    *(bf16x8*)(smem + ((tt) & 1) * 24576 + aoff) = vv; }
#define STG_B(tt) { char* db = uw + ((tt) & 1) * 24576 + 8192; const int kk = (tt) * 32; \
    gload_lds16(pB0 + kk, db); gload_lds16(pB1 + kk, db + 8192); }

    LDA_(a0_0, a1_0, 0);
    STG_B(0);
    LDA_(a0_1, a1_1, 1);
    VMW4();
    WRA_(a0_0, a1_0, 0);
    LGKM0();

#define AITER(tt, sL0, sL1, sW0, sW1) { \
    const bool hasL = (tt) + 2 < NT, hasB = (tt) + 1 < NT; \
    if (hasL) LDA_(sL0, sL1, (tt) + 2); \
    if (hasB) STG_B((tt) + 1); \
    if (hasL)      VMW4(); \
    else if (hasB) VMW2(); \
    else           VMW0(); \
    BAR(); \
    const char* aB = smem + ((tt) & 1) * 24576; \
    const char* bB = aB + 8192; \
    bf16x8 af[4], bfr[4]; \
    _Pragma("unroll") \
    for (int m = 0; m < 4; ++m) \
        af[m]  = *(const bf16x8*)(aB + (wrow * 64 + m * 16 + rl) * 64 + ko); \
    _Pragma("unroll") \
    for (int n = 0; n < 4; ++n) \
        bfr[n] = *(const bf16x8*)(bB + (wcol * 64 + n * 16 + rl) * 64 + ko); \
    __builtin_amdgcn_s_setprio(1); \
    _Pragma("unroll") \
    for (int m = 0; m < 4; ++m) \
        _Pragma("unroll") \
        for (int n = 0; n < 4; ++n) \
            acc[m][n] = __builtin_amdgcn_mfma_f32_16x16x32_bf16( \
                            af[m], bfr[n], acc[m][n], 0, 0, 0); \
    __builtin_amdgcn_s_setprio(0); \
    if (hasB) WRA_(sW0, sW1, (tt) + 1); \
    LGKM0(); \
    BAR(); }

    for (int tt = 0; tt < NT; tt += 2) {
        AITER(tt,     a0_0, a1_0, a0_1, a1_1);
        AITER(tt + 1, a0_1, a1_1, a0_0, a1_0);
    }
#undef AITER
#undef LDA_
#undef WRA_
#undef STG_B
}

// ---------------------------------------------------------------------------
// Merged QKV projections, 128x256 tiles: 1D grid 768, XCD-grouped so each
// XCD runs 8-block runs sharing one W panel (512KB, L2-resident) while
// sweeping its own 8 A-row panels.  (xcd = G&7; j = G>>3; bxn = j>>3;
// byn = xcd*8 + (j&7) — bijective.)
// ---------------------------------------------------------------------------
__global__ __launch_bounds__(512, 4)
void gemm_qkv(const float* __restrict__ Xq, const float* __restrict__ Xk,
              const float* __restrict__ Xv,
              const bf16* __restrict__ Wt3,
              float* __restrict__ outQ, bf16* __restrict__ Qb,
              bf16* __restrict__ Kb, bf16* __restrict__ Vt)
{
    extern __shared__ char smem[];
    const int G   = blockIdx.x;
    const int xcd = G & 7, j = G >> 3;     // j 0..95
    const int bxn = j >> 3;                // 0..11 (W panel)
    const int byn = xcd * 8 + (j & 7);     // 0..63 (A panel)
    const int mat = bxn >> 2, nc = bxn & 3;

    const float* A = (mat == 0 ? Xq : mat == 1 ? Xk : Xv) + (long long)byn * 128 * 1024;
    const bf16* B = Wt3 + (long long)mat * 1024 * 1024 + (long long)nc * 256 * 1024;
    f32x4 acc[4][4] = {};
    gemm_core_af32(A, B, 1024, 1024, 32, smem, acc);

    const int t = threadIdx.x, lane = t & 63, wid = t >> 6;
    const int wr = (wid >> 2) * 64, wc = (wid & 3) * 64;
    const int rl = lane & 15, rg4 = (lane >> 4) * 4;

    if (mat != 2) {
#pragma unroll
        for (int m = 0; m < 4; ++m)
#pragma unroll
            for (int n = 0; n < 4; ++n)
#pragma unroll
                for (int j2 = 0; j2 < 4; ++j2) {
                    const int row = byn * 128 + wr + m * 16 + rg4 + j2;
                    const int col = nc * 256 + wc + n * 16 + rl;
                    const float v = acc[m][n][j2];
                    if (mat == 0) { outQ[(long long)row * 1024 + col] = v;
                                    Qb[(long long)row * 1024 + col] = (bf16)v; }
                    else Kb[(long long)row * 1024 + col] = (bf16)v;
                }
    } else {
        // V: transpose via LDS (two 128-col halves; swizzled [128][128] bf16)
        char* lT = smem;
#pragma unroll
        for (int h = 0; h < 2; ++h) {
            BAR();
            if ((wc >> 7) == h) {
#pragma unroll
                for (int m = 0; m < 4; ++m)
#pragma unroll
                    for (int n = 0; n < 4; ++n) {
                        const int cp = (wc & 127) + n * 16 + rl;      // 0..127
                        const int rb = wr + m * 16 + rg4;             // 0..124
                        bf16x4 v;
                        v[0] = (bf16)acc[m][n][0]; v[1] = (bf16)acc[m][n][1];
                        v[2] = (bf16)acc[m][n][2]; v[3] = (bf16)acc[m][n][3];
                        *(bf16x4*)(lT + cp * 256 + ((rb * 2) ^ ((cp & 7) << 4))) = v;
                    }
            }
            BAR();
            const int c2 = t >> 2;
#pragma unroll
            for (int it = 0; it < 4; ++it) {
                const int q = (t & 3) + it * 4;                       // 0..15
                bf16x8 v = *(const bf16x8*)(lT + c2 * 256 + ((q << 4) ^ ((c2 & 7) << 4)));
                *(bf16x8*)(Vt + (long long)(nc * 256 + h * 128 + c2) * 8192
                              + byn * 128 + q * 8) = v;
            }
        }
    }
}

// ---------------------------------------------------------------------------
// QK^T causal, 128x256 tiles, COMPACT 1D grid 288, XCD-grouped: each XCD
// gets 36 bx-major pairs of one bz (Kb panel L2-resident; uniform load).
// Pair list bx-major: bx 0..7, by 2*bx..15.  Writes bf16 scores (ld 2048).
// ---------------------------------------------------------------------------
__constant__ signed char SCP_BX[72] = {
    0,0,0,0,0,0,0,0,0,0,0,0,0,0,0,0,
    1,1,1,1,1,1,1,1,1,1,1,1,1,1,
    2,2,2,2,2,2,2,2,2,2,2,2,
    3,3,3,3,3,3,3,3,3,3,
    4,4,4,4,4,4,4,4,
    5,5,5,5,5,5,
    6,6,6,6,
    7,7};
__constant__ signed char SCP_BY[72] = {
    0,1,2,3,4,5,6,7,8,9,10,11,12,13,14,15,
    2,3,4,5,6,7,8,9,10,11,12,13,14,15,
    4,5,6,7,8,9,10,11,12,13,14,15,
    6,7,8,9,10,11,12,13,14,15,
    8,9,10,11,12,13,14,15,
    10,11,12,13,14,15,
    12,13,14,15,
    14,15};

__global__ __launch_bounds__(512, 4)
void gemm_sc(const bf16* __restrict__ Qb, const bf16* __restrict__ Kb,
             bf16* __restrict__ scores, float scale)
{
    extern __shared__ char smem[];
    const int G   = blockIdx.x;            // 0..287
    const int xcd = G & 7, r = G >> 3;     // r 0..35
    const int u   = xcd * 36 + r;          // 0..287
    const int bz  = u / 72;
    const int pr  = u % 72;
    const int bx  = SCP_BX[pr], by = SCP_BY[pr];
    const long long boff = (long long)bz * 2048 * 1024;
    f32x4 acc[4][4] = {};
    gemm_core_bk32(Qb + boff + (long long)by * 128 * 1024,
                   Kb + boff + (long long)bx * 256 * 1024, 1024, 1024, 32, smem, acc);

    const int t = threadIdx.x, lane = t & 63, wid = t >> 6;
    const int wr = (wid >> 2) * 64, wc = (wid & 3) * 64;
    const int rl = lane & 15, rg4 = (lane >> 4) * 4;
    bf16* Cb = scores + (long long)bz * 2048 * 2048;
#pragma unroll
    for (int m = 0; m < 4; ++m)
#pragma unroll
        for (int n = 0; n < 4; ++n)
#pragma unroll
            for (int j = 0; j < 4; ++j) {
                const int row = by * 128 + wr + m * 16 + rg4 + j;
                const int col = bx * 256 + wc + n * 16 + rl;
                Cb[(long long)row * 2048 + col] = (bf16)(acc[m][n][j] * scale);
            }
}

// ---------------------------------------------------------------------------
// PV: 128x256 tiles, 1D grid 256, XCD-grouped: each XCD owns 2 fixed
// (bz,bx) combos x full by-sweep -> Vt panel L2-resident AND per-XCD load
// exactly uniform (2 x 544 slots).  NT = (by+1)*4 (K-limit).
// ---------------------------------------------------------------------------
__global__ __launch_bounds__(512, 4)
void gemm_pv(const bf16* __restrict__ P, const bf16* __restrict__ Vt,
             float* __restrict__ outA)
{
    extern __shared__ char smem[];
    const int G   = blockIdx.x;            // 0..255
    const int xcd = G & 7, r = G >> 3;     // r 0..31
    const int combo = xcd * 2 + (r >> 4);  // 0..15
    const int by  = r & 15;
    const int bz  = combo >> 2, bx = combo & 3;
    f32x4 acc[4][4] = {};
    gemm_core_bk32(P + (long long)bz * 2048 * 2048 + (long long)by * 128 * 2048,
                   Vt + (long long)bx * 256 * 8192 + (long long)bz * 2048,
                   2048, 8192, (by + 1) * 4, smem, acc);

    const int t = threadIdx.x, lane = t & 63, wid = t >> 6;
    const int wr = (wid >> 2) * 64, wc = (wid & 3) * 64;
    const int rl = lane & 15, rg4 = (lane >> 4) * 4;
    float* Cb = outA + (long long)bz * 2048 * 1024;
#pragma unroll
    for (int m = 0; m < 4; ++m)
#pragma unroll
        for (int n = 0; n < 4; ++n)
#pragma unroll
            for (int j = 0; j < 4; ++j) {
                const int row = by * 128 + wr + m * 16 + rg4 + j;
                const int col = bx * 256 + wc + n * 16 + rl;
                Cb[(long long)row * 1024 + col] = acc[m][n][j];
            }
}

// ---------------------------------------------------------------------------
// Transpose-convert all three W into contiguous Wt3[mat][n][k]: grid (32,32,3).
// ---------------------------------------------------------------------------
__global__ __launch_bounds__(256)
void transpose_w3(const float* __restrict__ W0, const float* __restrict__ W1,
                  const float* __restrict__ W2, bf16* __restrict__ Wt3)
{
    __shared__ float tile[32][33];
    const int w = blockIdx.z;
    const float* W = w == 0 ? W0 : w == 1 ? W1 : W2;
    bf16* Wt = Wt3 + (size_t)w * 1024 * 1024;
    const int bx = blockIdx.x * 32;
    const int by = blockIdx.y * 32;
    const int tx = threadIdx.x;
    const int ty = threadIdx.y;
    for (int i = ty; i < 32; i += 8)
        tile[i][tx] = W[(size_t)(by + i) * 1024 + bx + tx];
    __syncthreads();
    for (int i = ty; i < 32; i += 8)
        Wt[(size_t)(bx + i) * 1024 + by + tx] = (bf16)tile[tx][i];
}

// ---------------------------------------------------------------------------
// Causal row softmax over bf16 scores, in place, pure register pass.
// ---------------------------------------------------------------------------
__global__ __launch_bounds__(256)
void softmax_causal(bf16* __restrict__ scores)
{
    __shared__ float red[8];
    const int row = blockIdx.x;           // b*2048 + q
    const int q   = row & 2047;
    bf16* srow = scores + (size_t)row * 2048;
    const int L = q + 1;
    const int tileEnd = ((q >> 8) + 1) << 8;   // 256-aligned, >= L
    const int t = threadIdx.x, lane = t & 63, wv = t >> 6;
    const int k0 = t * 8;
    const bool act = k0 < tileEnd;

    float f[8];
    if (act) {
        bf16x8 v = *(const bf16x8*)(srow + k0);
#pragma unroll
        for (int i = 0; i < 8; ++i)
            f[i] = (k0 + i < L) ? (float)v[i] : -INFINITY;
    } else {
#pragma unroll
        for (int i = 0; i < 8; ++i) f[i] = -INFINITY;
    }
    float m = f[0];
#pragma unroll
    for (int i = 1; i < 8; ++i) m = fmaxf(m, f[i]);
#pragma unroll
    for (int o = 32; o; o >>= 1) m = fmaxf(m, __shfl_xor(m, o));
    if (lane == 0) red[wv] = m;
    __syncthreads();
    m = fmaxf(fmaxf(red[0], red[1]), fmaxf(red[2], red[3]));

    float s = 0.f;
#pragma unroll
    for (int i = 0; i < 8; ++i) { f[i] = __expf(f[i] - m); s += f[i]; }
#pragma unroll
    for (int o = 32; o; o >>= 1) s += __shfl_xor(s, o);
    if (lane == 0) red[4 + wv] = s;
    __syncthreads();
    s = (red[4] + red[5]) + (red[6] + red[7]);
    const float inv = 1.f / s;

    if (act) {
        bf16x8 o8;
#pragma unroll
        for (int i = 0; i < 8; ++i) o8[i] = (bf16)(f[i] * inv);
        *(bf16x8*)(srow + k0) = o8;
    }
}

// ---------------------------------------------------------------------------
// Launch.  Workspace map:
//   Qb @0 (16MB) | Kb @16 (16MB) | Vt @32 (16MB)
//   scores bf16 @48 (32MB) | Wt3 @80 (6MB)
// ---------------------------------------------------------------------------
extern "C" void kernel_launch(void* const* d_in, const int* in_sizes, int n_in,
                              void* d_out, int out_size, void* d_ws, size_t ws_size,
                              hipStream_t stream)
{
    const float* Xk = (const float*)d_in[0];
    const float* Xv = (const float*)d_in[1];
    const float* Xq = (const float*)d_in[2];
    const float* WK = (const float*)d_in[3];
    const float* WV = (const float*)d_in[4];
    const float* WQ = (const float*)d_in[5];

    float* outQ = (float*)d_out;                       // [4,2048,1024] f32
    float* outA = outQ + (size_t)8192 * 1024;          // [4,2048,1024] f32

    char* ws = (char*)d_ws;
    bf16*  Qb     = (bf16*)(ws);                       // 16MB
    bf16*  Kb     = (bf16*)(ws + (16ull << 20));       // 16MB
    bf16*  Vt     = (bf16*)(ws + (32ull << 20));       // 16MB  [1024][8192]
    bf16*  scores = (bf16*)(ws + (48ull << 20));       // 32MB  [4][2048][2048]
    bf16*  Wt3    = (bf16*)(ws + (80ull << 20));       // 6MB   [3][1024][1024]
    const float scale = 0.022097086912079608f;         // 1/sqrt(2048)

    hipFuncSetAttribute((const void*)gemm_qkv, hipFuncAttributeMaxDynamicSharedMemorySize, 49152);
    hipFuncSetAttribute((const void*)gemm_sc,  hipFuncAttributeMaxDynamicSharedMemorySize, 49152);
    hipFuncSetAttribute((const void*)gemm_pv,  hipFuncAttributeMaxDynamicSharedMemorySize, 49152);

    transpose_w3<<<dim3(32, 32, 3), dim3(32, 8), 0, stream>>>(WQ, WK, WV, Wt3);

    gemm_qkv<<<dim3(768), 512, 49152, stream>>>(
        Xq, Xk, Xv, Wt3, outQ, Qb, Kb, Vt);

    gemm_sc<<<dim3(288), 512, 49152, stream>>>(Qb, Kb, scores, scale);

    softmax_causal<<<dim3(8192), 256, 0, stream>>>(scores);

    gemm_pv<<<dim3(256), 512, 49152, stream>>>(scores, Vt, outA);
}